// Round 1
// 452.858 us; speedup vs baseline: 1.6257x; 1.6257x over previous
//
#include <hip/hip_runtime.h>
#include <stdint.h>

#define NFFT  1024
#define MROWS 32768
#define RPB   8          // rows per block
#define PADN  1088       // 1024 + 1024/16 padding slots

// LDS pad: +1 float per 16 — breaks the stride-4/16/64 bank conflicts of the
// Stockham scatter writes and the stride-64 twiddle reads down to <=2-3 way.
__device__ __forceinline__ int P(int a) { return a + (a >> 4); }

// forward radix-4 butterfly (DFT4 with e^{-2pi i kn/4})
__device__ __forceinline__ void dft4(float (&vr)[4], float (&vi)[4]) {
  const float t0r = vr[0] + vr[2], t0i = vi[0] + vi[2];
  const float t1r = vr[0] - vr[2], t1i = vi[0] - vi[2];
  const float t2r = vr[1] + vr[3], t2i = vi[1] + vi[3];
  const float t3r = vi[1] - vi[3], t3i = vr[3] - vr[1];   // -i*(v1 - v3)
  vr[0] = t0r + t2r; vi[0] = t0i + t2i;
  vr[1] = t1r + t3r; vi[1] = t1i + t3i;
  vr[2] = t0r - t2r; vi[2] = t0i - t2i;
  vr[3] = t1r - t3r; vi[3] = t1i - t3i;
}

// One Stockham radix-4 stage: read src[j + 256r], twiddle by
// exp(-2pi i * r*(j%NS)/(4*NS)) = tw[r*(j%NS)*STEP] (STEP = 256/NS),
// DFT4, write dst[(j/NS)*4NS + (j%NS) + r*NS]. Trailing barrier.
template<int NS, int STEP>
__device__ __forceinline__ void lds_stage(int j,
    const float* __restrict__ sr, const float* __restrict__ si,
    float* __restrict__ dr, float* __restrict__ di,
    const float* __restrict__ twr, const float* __restrict__ twi) {
  float vr[4], vi[4];
#pragma unroll
  for (int r = 0; r < 4; ++r) {
    vr[r] = sr[P(j + 256 * r)];
    vi[r] = si[P(j + 256 * r)];
  }
  const int m = j & (NS - 1);
#pragma unroll
  for (int r = 1; r < 4; ++r) {
    const int idx = P(r * m * STEP);
    const float c = twr[idx], d = twi[idx];
    const float nr = vr[r] * c - vi[r] * d;
    const float ni = vr[r] * d + vi[r] * c;
    vr[r] = nr; vi[r] = ni;
  }
  dft4(vr, vi);
  const int base = ((j & ~(NS - 1)) << 2) + m;   // (j/NS)*4NS + m
#pragma unroll
  for (int r = 0; r < 4; ++r) {
    dr[P(base + r * NS)] = vr[r];
    di[P(base + r * NS)] = vi[r];
  }
  __syncthreads();
}

// Batched 1024-pt complex forward FFT, one row per 256 threads, RPB rows/block.
// Twiddles come from row 1 of w_real/w_imag: w[1][n] = exp(-2pi i n/1024)
// exactly as the reference constructs them (float64 cos/sin -> f32).
__global__ void __launch_bounds__(256)
fft1024(const float* __restrict__ xr, const float* __restrict__ xi,
        const float* __restrict__ wr, const float* __restrict__ wi,
        const float* __restrict__ br, const float* __restrict__ bi,
        float* __restrict__ out) {
  __shared__ float twr[PADN], twi[PADN];
  __shared__ float d0r[PADN], d0i[PADN], d1r[PADN], d1i[PADN];

  const int j = threadIdx.x;   // 0..255

  // twiddle table: 8KB per array, L2/L3-resident after first blocks
  {
    const float4 cr = *(const float4*)(wr + NFFT + 4 * j);
    const float4 ci = *(const float4*)(wi + NFFT + 4 * j);
    twr[P(4 * j + 0)] = cr.x; twr[P(4 * j + 1)] = cr.y;
    twr[P(4 * j + 2)] = cr.z; twr[P(4 * j + 3)] = cr.w;
    twi[P(4 * j + 0)] = ci.x; twi[P(4 * j + 1)] = ci.y;
    twi[P(4 * j + 2)] = ci.z; twi[P(4 * j + 3)] = ci.w;
  }

  // bias folded once per block: this thread always writes cols j+256r
  //   real += br[c] - bi[c];  imag += br[c] + bi[c]
  float badd_r[4], badd_i[4];
#pragma unroll
  for (int r = 0; r < 4; ++r) {
    const int c = j + 256 * r;
    const float a = br[c], b = bi[c];
    badd_r[r] = a - b;
    badd_i[r] = a + b;
  }

  const int row0 = blockIdx.x * RPB;
  for (int rr = 0; rr < RPB; ++rr) {
    const size_t row = (size_t)(row0 + rr);
    const float* pr = xr + row * NFFT;
    const float* pi = xi + row * NFFT;

    float vr[4], vi[4];
    // ---- stage 0 (Ns=1): twiddles are all 1; gather straight from global
#pragma unroll
    for (int r = 0; r < 4; ++r) {
      vr[r] = pr[j + 256 * r];
      vi[r] = pi[j + 256 * r];
    }
    dft4(vr, vi);
#pragma unroll
    for (int r = 0; r < 4; ++r) {     // idxD = 4j + r
      d1r[P(4 * j + r)] = vr[r];
      d1i[P(4 * j + r)] = vi[r];
    }
    __syncthreads();

    // ---- stages 1..3 in LDS (ping-pong d1 -> d0 -> d1 -> d0)
    lds_stage<4, 64>(j, d1r, d1i, d0r, d0i, twr, twi);
    lds_stage<16, 16>(j, d0r, d0i, d1r, d1i, twr, twi);
    lds_stage<64, 4>(j, d1r, d1i, d0r, d0i, twr, twi);

    // ---- stage 4 (Ns=256): read d0, twiddle tw[r*j], write global + bias
#pragma unroll
    for (int r = 0; r < 4; ++r) {
      vr[r] = d0r[P(j + 256 * r)];
      vi[r] = d0i[P(j + 256 * r)];
    }
#pragma unroll
    for (int r = 1; r < 4; ++r) {
      const int idx = P(r * j);
      const float c = twr[idx], d = twi[idx];
      const float nr = vr[r] * c - vi[r] * d;
      const float ni = vr[r] * d + vi[r] * c;
      vr[r] = nr; vi[r] = ni;
    }
    dft4(vr, vi);
    float* o_r = out + row * NFFT;
    float* o_i = out + (size_t)MROWS * NFFT + row * NFFT;
#pragma unroll
    for (int r = 0; r < 4; ++r) {
      const int c = j + 256 * r;
      o_r[c] = vr[r] + badd_r[r];
      o_i[c] = vi[r] + badd_i[r];
    }
    // no extra barrier needed: next row's d1 writes are ordered after the
    // lds_stage<64,4> trailing barrier (last d1 readers), and next row's d0
    // writes sit behind the stage-0 trailing barrier (this stage-4's reads).
  }
}

extern "C" void kernel_launch(void* const* d_in, const int* in_sizes, int n_in,
                              void* d_out, int out_size, void* d_ws, size_t ws_size,
                              hipStream_t stream) {
  const float* xr = (const float*)d_in[0];
  const float* xi = (const float*)d_in[1];
  const float* wr = (const float*)d_in[2];
  const float* wi = (const float*)d_in[3];
  const float* br = (const float*)d_in[4];
  const float* bi = (const float*)d_in[5];
  float* out = (float*)d_out;
  (void)in_sizes; (void)n_in; (void)out_size; (void)d_ws; (void)ws_size;

  fft1024<<<MROWS / RPB, 256, 0, stream>>>(xr, xi, wr, wi, br, bi, out);
}